// Round 4
// baseline (139.623 us; speedup 1.0000x reference)
//
#include <hip/hip_runtime.h>
#include <math.h>

// out = gelu(rowmean(x@W^T - subtract) + logN) + x
// rowmean(x@W^T)[m] = (1/N) * dot(x[m,:], colsum(W)).  No GEMM needed.

typedef float f4 __attribute__((ext_vector_type(4)));

// Kernel A: wsum[k] = sum_n W[n,k] (atomics over row-chunks).
// Last grid.y slice (blockIdx.x==0) also computes submean = mean(subtract).
__global__ __launch_bounds__(256) void colsum_kernel(
    const float* __restrict__ w, const float* __restrict__ sub,
    float* __restrict__ wsum, float* __restrict__ submean,
    int N, int K, int rows_per_block, float invN) {
    if (blockIdx.y == gridDim.y - 1) {
        if (blockIdx.x != 0) return;
        float acc = 0.f;
        for (int i = threadIdx.x; i < N; i += 256) acc += sub[i];
        #pragma unroll
        for (int off = 32; off > 0; off >>= 1) acc += __shfl_down(acc, off, 64);
        __shared__ float sd[4];
        if ((threadIdx.x & 63) == 0) sd[threadIdx.x >> 6] = acc;
        __syncthreads();
        if (threadIdx.x == 0) submean[0] = (sd[0] + sd[1] + sd[2] + sd[3]) * invN;
        return;
    }
    const int K4 = K >> 2;
    const int col4 = blockIdx.x * blockDim.x + threadIdx.x;
    if (col4 >= K4) return;
    const int row0 = blockIdx.y * rows_per_block;
    int row1 = row0 + rows_per_block;
    if (row1 > N) row1 = N;
    const f4* w4 = (const f4*)w;
    f4 acc = (f4)(0.f);
    for (int n = row0; n < row1; ++n) {
        acc += __builtin_nontemporal_load(&w4[(size_t)n * K4 + col4]);
    }
    float* dst = wsum + (size_t)col4 * 4;
    atomicAdd(dst + 0, acc.x);
    atomicAdd(dst + 1, acc.y);
    atomicAdd(dst + 2, acc.z);
    atomicAdd(dst + 3, acc.w);
}

// Kernel B: TWO rows per wave, software-pipelined.
// All 32 x-loads issued up front (row B in flight through row A's work);
// one register-transient wsum pass computes both dots; two interleaved
// shuffle-reduce chains; two store bursts.
__global__ __launch_bounds__(256) void fused_row_kernel(
    const float* __restrict__ x, const float* __restrict__ wsum,
    const float* __restrict__ submean_p, float* __restrict__ out,
    int M, int K, float logN, float invN) {
    const int lane = threadIdx.x & 63;
    const int wid  = blockIdx.x * 4 + (threadIdx.x >> 6);
    const int r0 = wid * 2;
    if (r0 >= M) return;
    const f4* xa  = (const f4*)(x + (size_t)r0 * K);
    const f4* xb  = (const f4*)(x + (size_t)(r0 + 1) * K);
    const f4* ws4 = (const f4*)wsum;

    f4 a[16], b[16];
    #pragma unroll
    for (int j = 0; j < 16; ++j)
        a[j] = __builtin_nontemporal_load(&xa[j * 64 + lane]);
    #pragma unroll
    for (int j = 0; j < 16; ++j)
        b[j] = __builtin_nontemporal_load(&xb[j * 64 + lane]);

    float dota = 0.f, dotb = 0.f;
    #pragma unroll
    for (int j = 0; j < 16; ++j) {
        const f4 w = ws4[j * 64 + lane];            // L1-resident (16 KB)
        dota = fmaf(a[j].x, w.x, fmaf(a[j].y, w.y,
               fmaf(a[j].z, w.z, fmaf(a[j].w, w.w, dota))));
        dotb = fmaf(b[j].x, w.x, fmaf(b[j].y, w.y,
               fmaf(b[j].z, w.z, fmaf(b[j].w, w.w, dotb))));
    }

    #pragma unroll
    for (int off = 1; off < 64; off <<= 1) {
        dota += __shfl_xor(dota, off, 64);
        dotb += __shfl_xor(dotb, off, 64);
    }

    const float sm = submean_p[0];
    const float ca = dota * invN - sm + logN;
    const float cb = dotb * invN - sm + logN;
    const float ta = 0.7978845608028654f * fmaf(0.044715f * ca, ca * ca, ca);
    const float tb = 0.7978845608028654f * fmaf(0.044715f * cb, cb * cb, cb);
    const float ga = 0.5f * ca * (1.f + ta / (fabsf(ta) + 1.f));
    const float gb = 0.5f * cb * (1.f + tb / (fabsf(tb) + 1.f));

    f4* oa = (f4*)(out + (size_t)r0 * K);
    f4* ob = (f4*)(out + (size_t)(r0 + 1) * K);
    #pragma unroll
    for (int j = 0; j < 16; ++j)
        __builtin_nontemporal_store(a[j] + (f4)(ga), &oa[j * 64 + lane]);
    #pragma unroll
    for (int j = 0; j < 16; ++j)
        __builtin_nontemporal_store(b[j] + (f4)(gb), &ob[j * 64 + lane]);
}

extern "C" void kernel_launch(void* const* d_in, const int* in_sizes, int n_in,
                              void* d_out, int out_size, void* d_ws, size_t ws_size,
                              hipStream_t stream) {
    const float* x   = (const float*)d_in[0];
    const float* w   = (const float*)d_in[1];
    const float* sub = (const float*)d_in[2];
    float* out = (float*)d_out;

    const int N = in_sizes[2];            // 4096
    const int K = in_sizes[1] / N;        // 4096
    const int M = in_sizes[0] / K;        // 16384

    float* wsum    = (float*)d_ws;        // K floats
    float* submean = wsum + K;            // 1 float

    (void)hipMemsetAsync(d_ws, 0, (size_t)(K + 1) * sizeof(float), stream);

    const int K4 = K / 4;
    const int rows_per_block = 64;
    dim3 gA((K4 + 255) / 256, N / rows_per_block + 1);
    colsum_kernel<<<gA, 256, 0, stream>>>(w, sub, wsum, submean,
                                          N, K, rows_per_block, 1.0f / (float)N);

    // 2 rows per wave, 4 waves per block -> 8 rows per block
    fused_row_kernel<<<(M + 7) / 8, 256, 0, stream>>>(
        x, wsum, submean, out, M, K, logf((float)N), 1.0f / (float)N);
}